// Round 11
// baseline (432.118 us; speedup 1.0000x reference)
//
#include <hip/hip_runtime.h>
#include <stdint.h>

// W8A8B32O32 Linear: y[m][n] = sum_k x[m][k]*w[n][k] + bias[n]
// M=8192, N=4096, K=4096. Inputs arrive as int32 (one int per logical int8
// element); pack to int8 in d_ws, then run the i8 MFMA GEMM.
#define M_TOT 8192
#define N_TOT 4096
#define K_TOT 4096

typedef int v4i  __attribute__((ext_vector_type(4)));
typedef int v16i __attribute__((ext_vector_type(16)));

__device__ __forceinline__ void gload_lds16(const void* g, void* l) {
    __builtin_amdgcn_global_load_lds(
        (const __attribute__((address_space(1))) unsigned int*)g,
        (__attribute__((address_space(3))) unsigned int*)l,
        16, 0, 0);
}

// gfx9 s_waitcnt simm16: vmcnt[3:0]@[3:0], expcnt@[6:4], lgkmcnt@[11:8],
// vmcnt[5:4]@[15:14].
#define WAIT_V2_L0() __builtin_amdgcn_s_waitcnt(0x0072)  // vmcnt(2) lgkmcnt(0)
#define WAIT_V0_L0() __builtin_amdgcn_s_waitcnt(0x0070)  // vmcnt(0) lgkmcnt(0)
#define WAIT_V4()    __builtin_amdgcn_s_waitcnt(0x0f74)  // vmcnt(4), lgkm free
#define SBAR()       __builtin_amdgcn_s_barrier()
#define SFENCE()     __builtin_amdgcn_sched_barrier(0)

// ---- fused pack int32 -> int8: 64B loads -> 16B store per thread-iter ----
// BW-bound at 240 MB (~45 us); proven at the traffic floor (R3-R9).
__global__ __launch_bounds__(256) void pack2(
        const int4* __restrict__ xs, int4* __restrict__ xd,
        const int4* __restrict__ ws, int4* __restrict__ wd) {
    const int t = blockIdx.x * 256 + threadIdx.x;       // 0..524287
#pragma unroll
    for (int it = 0; it < 6; ++it) {
        const long g = (long)it * 524288 + t;
        const int4* __restrict__ src = (it < 4) ? xs : ws;
        int4* __restrict__ dst       = (it < 4) ? xd : wd;
        const long o = (it < 4) ? g : g - 2097152;
        int4 r;
        int* rp = (int*)&r;
#pragma unroll
        for (int q = 0; q < 4; ++q) {
            const int4 a = src[o * 4 + q];
            rp[q] = (a.x & 255) | ((a.y & 255) << 8) |
                    ((a.z & 255) << 16) | (a.w << 24);
        }
        dst[o] = r;
    }
}

// ---- GEMM: 256 threads = 4 waves, 128x128 tile, 3 blocks/CU --------------
// R10 post-mortem: antiphase within a barrier-coupled pair regressed (153us)
// -- the barrier re-syncs the pair no matter the intra-iter order. Session
// evidence: EVERY schedule/layout/pipe-balance variant lands at 42-48% util;
// single-wave duty cycle is ~45% structurally (R0), and +1 COUPLED wave
// bought only +6 (R4). The untried axis is INDEPENDENT contexts per SIMD:
// all prior configs carried >=228 unified regs (128-256 AGPR acc) -> hard
// 2 waves/SIMD cap. This version: 4-wave block, wave-tile 64x64 -> acc =
// 2x2 v16i = 64 AGPR, ~80 VGPR => ~144 unified; __launch_bounds__(256,3)
// => 3 waves/SIMD, each from a DIFFERENT block (LDS 48 KB/block => exactly
// 3 blocks/CU). One block's barrier/vmcnt stall is covered by the other
// two blocks' MFMA streams -- TLP instead of program-level tricks.
//
// K-loop = R4's proven cadence verbatim (triple buffer, counted vmcnt,
// 2-phase kk split), frag counts halved. Per K-iter, per wave:
//   s1) 4 ds_read: kk=1 frags -> a1/b1      (hidden under s3)
//   s2) 2 A-DMAs of tile kt+2
//   s3) 4 MFMA kk=0 (setprio)
//   s4) s_waitcnt vmcnt(2) lgkmcnt(0); s_barrier
//       [tile kt+1 fully landed (A2's 2 stay in flight); my reads retired]
//   s5) 4 ds_read: kk=0 of tile kt+1 -> a0/b0 (hidden under s7)
//   s6) 2 B-DMAs of tile kt+2
//   s7) 4 MFMA kk=1 (setprio)
//   rotate 3 buffers.
// vmcnt ledger at s4: outstanding = A(kt+1)2+B(kt+1)2 (issued prev iter) +
// A(kt+2)2 = 6 -> vmcnt(2) == tile kt+1 landed (in-order decrement). Tail
// (kt+2>=NT): vmcnt(0). Buffer-reuse proof: s2/s6 DMAs target the buffer of
// tile kt-1, whose last reads (iter kt-1) were retired by iter kt-1's s4
// lgkmcnt(0) in EVERY wave before its barrier; our issue is after. s5 reads
// of kt+1 follow each wave's own vmcnt drain + the same barrier. Explicit
// waits REQUIRED: compiler alias analysis does not connect global_load_lds's
// LDS write to the ds_reads.
// Staging (row-major 64-B rows, 2-bit XOR chunk swizzle, R4-proven):
// stored_chunk = logical_chunk ^ ((row>>1)&3); issue i covers rows
// i*16+(lane>>2); fetch chunk fc = (lane&3)^((lane>>3)&3); coalesced 64-B
// row segments, linear LDS dst. Fragment reads: row = base + l31 (bases
// mult of 8) -> swr = (l31>>1)&3; logical chunk kk*2+kh at slot
// (kk*2+kh)^swr. Residual conflicts are hidden (R6 measured).
__global__ __launch_bounds__(256, 3) void i8gemm_bias(
        const signed char* __restrict__ x,
        const signed char* __restrict__ w,
        const int* __restrict__ bias,
        int* __restrict__ out) {
    __shared__ __align__(16) signed char la[3][128 * 64];
    __shared__ __align__(16) signed char lb[3][128 * 64];

    const int tid  = threadIdx.x;
    const int lane = tid & 63;           // 0..63
    const int wv   = tid >> 6;           // wave 0..3
    const int l31  = lane & 31;
    const int kh   = lane >> 5;          // K-half this lane supplies to MFMA
    const int wr   = wv >> 1;            // quadrant row (0..1) -> 64 rows
    const int wc   = wv & 1;             // quadrant col (0..1) -> 64 cols

    // XCD-aware bijective swizzle (2048 blocks, 2048%8==0): XCD k gets 256
    // consecutive swz = 8 A-row-panels x all 32 B-col-blocks.
    const int flat = blockIdx.y * gridDim.x + blockIdx.x;   // 0..2047
    const int swz  = (flat & 7) * 256 + (flat >> 3);
    const int bn0  = (swz & 31) * 128;
    const int bm0  = (swz >> 5) * 128;

    // Fused bias: C/D col = lane&31 -> bias is lane-constant per fragment.
    int bv[2];
#pragma unroll
    for (int j = 0; j < 2; ++j) bv[j] = bias[bn0 + wc * 64 + j * 32 + l31];
    v16i acc[2][2];
#pragma unroll
    for (int i = 0; i < 2; ++i)
#pragma unroll
        for (int j = 0; j < 2; ++j)
#pragma unroll
            for (int r = 0; r < 16; ++r) acc[i][j][r] = bv[j];

    // Staging: wave wv covers rows [wv*32, wv*32+32) of both A and B tiles:
    // 2 issues x (16 rows x 4 chunks) each.
    const int fc = (lane & 3) ^ ((lane >> 3) & 3);
    const signed char* pa = x + (long)(bm0 + wv * 32 + (lane >> 2)) * K_TOT + fc * 16;
    const signed char* pb = w + (long)(bn0 + wv * 32 + (lane >> 2)) * K_TOT + fc * 16;
    const int sdst = wv * 32 * 64;       // + i*1024 per issue i

    // Fragment reads: A row = wr*64 + i*32 + l31, B row = wc*64 + j*32 + l31.
    const int swr  = (l31 >> 1) & 3;
    const int aoff = (wr * 64 + l31) * 64;
    const int boff = (wc * 64 + l31) * 64;
    const int cs0  = ((0 + kh) ^ swr) * 16;   // kk=0 chunk byte offset
    const int cs1  = ((2 + kh) ^ swr) * 16;   // kk=1 chunk byte offset

    // Rotating buffer pointers: A0/B0 = tile kt, A1/B1 = kt+1, A2/B2 = kt+2.
    signed char* A0 = &la[0][0]; signed char* A1 = &la[1][0]; signed char* A2 = &la[2][0];
    signed char* B0 = &lb[0][0]; signed char* B1 = &lb[1][0]; signed char* B2 = &lb[2][0];

    // Prologue: stage tile 0 then tile 1 (grouped per tile: vmcnt decrements
    // in issue order). 4 DMAs per tile per wave (2 A + 2 B).
#pragma unroll
    for (int i = 0; i < 2; ++i) {
        gload_lds16(pa + (long)i * 16 * K_TOT, A0 + sdst + i * 1024);
        gload_lds16(pb + (long)i * 16 * K_TOT, B0 + sdst + i * 1024);
    }
#pragma unroll
    for (int i = 0; i < 2; ++i) {
        gload_lds16(pa + 64 + (long)i * 16 * K_TOT, A1 + sdst + i * 1024);
        gload_lds16(pb + 64 + (long)i * 16 * K_TOT, B1 + sdst + i * 1024);
    }
    WAIT_V4();                 // tile 0 landed (tile 1's 4 stay in flight)
    SBAR();
    SFENCE();

    // Preload kk=0 fragments of tile 0.
    v4i a0[2], b0[2], a1[2], b1[2];
#pragma unroll
    for (int i = 0; i < 2; ++i) a0[i] = *(const v4i*)(A0 + aoff + i * 2048 + cs0);
#pragma unroll
    for (int j = 0; j < 2; ++j) b0[j] = *(const v4i*)(B0 + boff + j * 2048 + cs0);

    const int NT = K_TOT / 64;           // 64 K-tiles
    for (int kt = 0; kt < NT; ++kt) {
        SFENCE();
        // s1) ds_read kk=1 of tile kt (consumed by s7; hidden by s3).
#pragma unroll
        for (int i = 0; i < 2; ++i) a1[i] = *(const v4i*)(A0 + aoff + i * 2048 + cs1);
#pragma unroll
        for (int j = 0; j < 2; ++j) b1[j] = *(const v4i*)(B0 + boff + j * 2048 + cs1);
        SFENCE();
        // s2) Issue A-half prefetch of tile kt+2 (fire-and-forget).
        if (kt + 2 < NT) {
            const long k0 = (long)(kt + 2) * 64;
#pragma unroll
            for (int i = 0; i < 2; ++i)
                gload_lds16(pa + k0 + (long)i * 16 * K_TOT, A2 + sdst + i * 1024);
        }
        SFENCE();
        // s3) MFMA kk=0 (4): hides s1 reads and s2 issues.
        __builtin_amdgcn_s_setprio(1);
#pragma unroll
        for (int i = 0; i < 2; ++i)
#pragma unroll
            for (int j = 0; j < 2; ++j)
                acc[i][j] = __builtin_amdgcn_mfma_i32_32x32x32_i8(
                    a0[i], b0[j], acc[i][j], 0, 0, 0);
        __builtin_amdgcn_s_setprio(0);
        SFENCE();
        // s4) Publish/acquire: tile kt+1 landed everywhere, my reads retired.
        if (kt + 2 < NT) { WAIT_V2_L0(); } else { WAIT_V0_L0(); }
        SFENCE();
        SBAR();
        SFENCE();
        // s5) ds_read kk=0 of tile kt+1 (hidden by s7).
        if (kt + 1 < NT) {
#pragma unroll
            for (int i = 0; i < 2; ++i) a0[i] = *(const v4i*)(A1 + aoff + i * 2048 + cs0);
#pragma unroll
            for (int j = 0; j < 2; ++j) b0[j] = *(const v4i*)(B1 + boff + j * 2048 + cs0);
        }
        SFENCE();
        // s6) Issue B-half prefetch of tile kt+2 (fire-and-forget).
        if (kt + 2 < NT) {
            const long k0 = (long)(kt + 2) * 64;
#pragma unroll
            for (int i = 0; i < 2; ++i)
                gload_lds16(pb + k0 + (long)i * 16 * K_TOT, B2 + sdst + i * 1024);
        }
        SFENCE();
        // s7) MFMA kk=1 (4): hides s5 reads (a1/b1 drained at s4).
        __builtin_amdgcn_s_setprio(1);
#pragma unroll
        for (int i = 0; i < 2; ++i)
#pragma unroll
            for (int j = 0; j < 2; ++j)
                acc[i][j] = __builtin_amdgcn_mfma_i32_32x32x32_i8(
                    a1[i], b1[j], acc[i][j], 0, 0, 0);
        __builtin_amdgcn_s_setprio(0);

        // Rotate buffers (register pointer swap, no dynamic indexing).
        signed char* t;
        t = A0; A0 = A1; A1 = A2; A2 = t;
        t = B0; B0 = B1; B1 = B2; B2 = t;
    }

    // Epilogue: C/D layout col=lane&31, row=(reg&3)+8*(reg>>2)+4*(lane>>5).
#pragma unroll
    for (int i = 0; i < 2; ++i) {
        const int mbase = bm0 + wr * 64 + i * 32 + 4 * kh;
#pragma unroll
        for (int j = 0; j < 2; ++j) {
            const int n = bn0 + wc * 64 + j * 32 + l31;
#pragma unroll
            for (int r = 0; r < 16; ++r) {
                const int m = mbase + (r & 3) + 8 * (r >> 2);
                out[(long)m * N_TOT + n] = acc[i][j][r];
            }
        }
    }
}

extern "C" void kernel_launch(void* const* d_in, const int* in_sizes, int n_in,
                              void* d_out, int out_size, void* d_ws, size_t ws_size,
                              hipStream_t stream) {
    const int* x32  = (const int*)d_in[0];  // [8192,4096] logical i8 as i32
    const int* w32  = (const int*)d_in[1];  // [4096,4096] logical i8 as i32
    const int* bias = (const int*)d_in[2];  // [4096] i32
    int*       out  = (int*)d_out;          // [8192,4096] i32

    signed char* xp = (signed char*)d_ws;
    signed char* wp = (signed char*)d_ws + (size_t)M_TOT * K_TOT;

    pack2<<<2048, 256, 0, stream>>>((const int4*)x32, (int4*)xp,
                                    (const int4*)w32, (int4*)wp);

    dim3 grid(N_TOT / 128, M_TOT / 128);  // (32, 64) = 2048 blocks
    i8gemm_bias<<<grid, 256, 0, stream>>>(xp, wp, bias, out);
}

// Round 12
// 408.895 us; speedup vs baseline: 1.0568x; 1.0568x over previous
//
#include <hip/hip_runtime.h>
#include <stdint.h>

// W8A8B32O32 Linear: y[m][n] = sum_k x[m][k]*w[n][k] + bias[n]
// M=8192, N=4096, K=4096. Inputs arrive as int32 (one int per logical int8
// element); pack to int8 in d_ws (W additionally SHUFFLED to MFMA fragment
// order), then run the i8 MFMA GEMM with B streamed global->VGPR.
#define M_TOT 8192
#define N_TOT 4096
#define K_TOT 4096

typedef int v4i  __attribute__((ext_vector_type(4)));
typedef int v16i __attribute__((ext_vector_type(16)));

__device__ __forceinline__ void gload_lds16(const void* g, void* l) {
    __builtin_amdgcn_global_load_lds(
        (const __attribute__((address_space(1))) unsigned int*)g,
        (__attribute__((address_space(3))) unsigned int*)l,
        16, 0, 0);
}

// gfx9 s_waitcnt simm16: vmcnt[3:0]@[3:0], expcnt@[6:4], lgkmcnt@[11:8].
#define WAIT_V6()  __builtin_amdgcn_s_waitcnt(0x0f76)  // vmcnt(6), lgkm free
#define SBAR()     __builtin_amdgcn_s_barrier()
#define SFENCE()   __builtin_amdgcn_sched_barrier(0)
#define MM(A, B, C) __builtin_amdgcn_mfma_i32_32x32x32_i8((A), (B), (C), 0, 0, 0)

// ---- pack + shuffle (R9-proven) ------------------------------------------
// x: plain pack. w: pack + shuffle to flatmm fragment order: 16-B slot
// q = ((nb*32 + ktb)*8 + s)*32 + l31 (s = slice*2+kh) holds
// w[nb*32+l31][ktb*128 + s*16 .. +16] -> B-frag = one contiguous 1-KB
// wave-load in the GEMM. For BK=64 tiles: offset advances 2048/tile.
__global__ __launch_bounds__(256) void pack2(
        const int4* __restrict__ xs, int4* __restrict__ xd,
        const int4* __restrict__ ws, int4* __restrict__ wd) {
    const int t = blockIdx.x * 256 + threadIdx.x;       // 0..524287
#pragma unroll
    for (int it = 0; it < 4; ++it) {
        const long o = (long)it * 524288 + t;
        int4 r; int* rp = (int*)&r;
#pragma unroll
        for (int q = 0; q < 4; ++q) {
            const int4 a = xs[o * 4 + q];
            rp[q] = (a.x & 255) | ((a.y & 255) << 8) |
                    ((a.z & 255) << 16) | (a.w << 24);
        }
        xd[o] = r;
    }
#pragma unroll
    for (int it = 0; it < 2; ++it) {
        const int q   = it * 524288 + t;       // 0..1048575
        const int l   = q & 31;
        const int s   = (q >> 5) & 7;
        const int ktb = (q >> 8) & 31;
        const int nb  = q >> 13;
        const long src = (long)(nb * 32 + l) * 1024 + ktb * 32 + s * 4;
        int4 r; int* rp = (int*)&r;
#pragma unroll
        for (int qq = 0; qq < 4; ++qq) {
            const int4 a = ws[src + qq];
            rp[qq] = (a.x & 255) | ((a.y & 255) << 8) |
                     ((a.z & 255) << 16) | (a.w << 24);
        }
        wd[q] = r;
    }
}

// ---- GEMM: 512 threads = 8 waves (2/SIMD), 256x256 tile, BK=64 -----------
// FINE-GRAINED 8-PHASE (m201-faithful). R5's failure was the COARSE split
// (vmcnt+bar each phase, bunched reads) -- documented as hurting; the fine
// interleave (2 ds_reads + 1 VMEM issue per phase, raw BAR, small MFMA
// cluster, BAR) is the one structure measured +28-41% over 2-phase, and is
// what setprio gates on. B comes from the pre-shuffled layout (R9-proven):
// LDS serves A only (3 x 16 KB triple buffer, 48 KB).
//
// Per K-tile kt (4 phases x {reads; 1 VMEM issue; BAR; 4 MFMA; BAR}):
//  ph0: ds a0[0..1](cs0); DMA-A iss0 (kt+2 -> T2) | MFMA kk0 x i={0,1}
//  ph1: ds a0[2..3](cs0); DMA-A iss1 (kt+2 -> T2) | MFMA kk0 x i={2,3}
//  ph2: ds a1[0..1](cs1); load bn kk0 (b of kt+1) | MFMA kk1 x i={0,1}
//  ph3: ds a1[2..3](cs1); load bn kk1, qb += 2048 | MFMA kk1 x i={2,3}
//  rotate T0<-T1<-T2; swap bc/bn via 2x unroll.
//
// NO explicit vmcnt in the loop -- the ordering proof:
//  (1) A(j+1)-ready: A(j+1) DMAs issue at iter j-1 ph0/ph1; b(j) loads issue
//      at iter j-1 ph2/ph3 (AFTER). The compiler's counted vmcnt before
//      iter j ph0's MFMA (consumes b(j), register dep) drains b(j) and
//      therefore A(j+1). Iter j+1 ph0's ds_reads of T(j+1) follow iter j
//      ph3's final barrier -> every wave's A(j+1) drained. Holds for all j
//      incl. tails (guards remove issues, not consumption).
//  (2) Reuse (write-after-read): DMA at iter j ph0 targets buf[(j+2)%3] =
//      tile j-1's buffer; its last reads (iter j-1 ph2/ph3) are consumed by
//      iter j-1 ph3's MFMA (compiler lgkm drain) before iter j-1's final
//      barrier; the DMA issues after it.
//  (3) SFENCE (sched_barrier 0) pins every phase boundary so the issue
//      order the proofs rely on is the emitted order.
// Prologue only: vmcnt(6) drains A(0) (A(1)x2 + b(0)x4 stay in flight).
// A staging/fragment math is R4-proven verbatim (row-major 64-B rows, 2-bit
// XOR chunk swizzle; residual 4-way conflicts measured-hidden in R6).
__global__ __launch_bounds__(512, 2) void i8gemm_bias(
        const signed char* __restrict__ x,
        const signed char* __restrict__ wshuf,
        const int* __restrict__ bias,
        int* __restrict__ out) {
    __shared__ __align__(16) signed char la[3][256 * 64];

    const int tid  = threadIdx.x;
    const int lane = tid & 63;           // 0..63
    const int wv   = tid >> 6;           // wave 0..7
    const int l31  = lane & 31;
    const int kh   = lane >> 5;          // K-half this lane supplies to MFMA
    const int wr   = wv >> 2;            // quadrant row (0..1) -> 128 rows
    const int wc   = wv & 3;             // quadrant col (0..3) -> 64 cols

    // XCD-aware bijective swizzle (512 blocks, 512%8==0).
    const int flat = blockIdx.y * gridDim.x + blockIdx.x;   // 0..511
    const int swz  = (flat & 7) * 64 + (flat >> 3);
    const int bn0  = (swz & 15) * 256;
    const int bm0  = (swz >> 4) * 256;

    // Fused bias: C/D col = lane&31 -> bias is lane-constant per fragment.
    int bv[2];
#pragma unroll
    for (int j = 0; j < 2; ++j) bv[j] = bias[bn0 + wc * 64 + j * 32 + l31];
    v16i acc[4][2];
#pragma unroll
    for (int i = 0; i < 4; ++i)
#pragma unroll
        for (int j = 0; j < 2; ++j)
#pragma unroll
            for (int r = 0; r < 16; ++r) acc[i][j][r] = bv[j];

    // A staging (R4): wave wv covers rows [wv*32, wv*32+32): 2 issues x
    // (16 rows x 4 chunks); stored chunk = lane&3, fetch chunk fc.
    const int fc = (lane & 3) ^ ((lane >> 3) & 3);
    const signed char* pa = x + (long)(bm0 + wv * 32 + (lane >> 2)) * K_TOT + fc * 16;
    const int sdst = wv * 32 * 64;       // + i*1024 per issue i

    // A fragment reads: row = wr*128 + i*32 + l31; swr = (l31>>1)&3.
    const int swr  = (l31 >> 1) & 3;
    const int aoff = (wr * 128 + l31) * 64;
    const int cs0  = ((0 + kh) ^ swr) * 16;   // kk=0 chunk byte offset
    const int cs1  = ((2 + kh) ^ swr) * 16;   // kk=1 chunk byte offset
#define RD_A(T, i, cs) (*(const v4i*)((T) + aoff + (i) * 2048 + (cs)))

    // B shuffled-layout bases (R9): frag j in N-block nbB+j; per tile (BK=64)
    // the offset advances 2048; kk adds 1024; lane adds lane*16.
    const int nbB = (bn0 >> 5) + wc * 2;
    const signed char* qb0 = wshuf + (long)nbB * 131072 + lane * 16;
    const signed char* qb1 = qb0 + 131072;

    // Triple buffer (A only): T0 = tile kt, T1 = kt+1, T2 = kt+2 dest.
    signed char* T0 = &la[0][0]; signed char* T1 = &la[1][0]; signed char* T2 = &la[2][0];

    // Prologue: A(0) 2 DMAs -> T0, A(1) 2 DMAs -> T1, then b(0) 4 loads
    // (strictly after, so the vmcnt queue is [A0][A1][b0]).
    gload_lds16(pa,                 T0 + sdst);
    gload_lds16(pa + 16L * K_TOT,   T0 + sdst + 1024);
    gload_lds16(pa + 64,            T1 + sdst);
    gload_lds16(pa + 64 + 16L * K_TOT, T1 + sdst + 1024);
    SFENCE();
    v4i bc0[2], bc1[2], bn0r[2], bn1r[2];
    bc0[0] = *(const v4i*)(qb0);        bc0[1] = *(const v4i*)(qb1);
    bc1[0] = *(const v4i*)(qb0 + 1024); bc1[1] = *(const v4i*)(qb1 + 1024);
    qb0 += 2048; qb1 += 2048;
    SFENCE();
    WAIT_V6();                 // A(0) landed; A(1)+b(0) stay in flight
    SBAR();
    SFENCE();

    v4i a0[4], a1[4];
    const int NT = K_TOT / 64;           // 64 K-tiles

#define TILE(BC0, BC1, BN0, BN1, KT)                                        \
do {                                                                        \
    const long kdma = (long)((KT) + 2) * 64;                                \
    /* ph0 */                                                               \
    a0[0] = RD_A(T0, 0, cs0);  a0[1] = RD_A(T0, 1, cs0);                    \
    if ((KT) + 2 < NT) gload_lds16(pa + kdma, T2 + sdst);                   \
    SFENCE(); SBAR();                                                       \
    __builtin_amdgcn_s_setprio(1);                                          \
    acc[0][0] = MM(a0[0], BC0[0], acc[0][0]);                               \
    acc[0][1] = MM(a0[0], BC0[1], acc[0][1]);                               \
    acc[1][0] = MM(a0[1], BC0[0], acc[1][0]);                               \
    acc[1][1] = MM(a0[1], BC0[1], acc[1][1]);                               \
    __builtin_amdgcn_s_setprio(0);                                          \
    SFENCE(); SBAR(); SFENCE();                                             \
    /* ph1 */                                                               \
    a0[2] = RD_A(T0, 2, cs0);  a0[3] = RD_A(T0, 3, cs0);                    \
    if ((KT) + 2 < NT) gload_lds16(pa + kdma + 16L * K_TOT,                 \
                                   T2 + sdst + 1024);                       \
    SFENCE(); SBAR();                                                       \
    __builtin_amdgcn_s_setprio(1);                                          \
    acc[2][0] = MM(a0[2], BC0[0], acc[2][0]);                               \
    acc[2][1] = MM(a0[2], BC0[1], acc[2][1]);                               \
    acc[3][0] = MM(a0[3], BC0[0], acc[3][0]);                               \
    acc[3][1] = MM(a0[3], BC0[1], acc[3][1]);                               \
    __builtin_amdgcn_s_setprio(0);                                          \
    SFENCE(); SBAR(); SFENCE();                                             \
    /* ph2 */                                                               \
    a1[0] = RD_A(T0, 0, cs1);  a1[1] = RD_A(T0, 1, cs1);                    \
    if ((KT) + 1 < NT) { BN0[0] = *(const v4i*)(qb0);                       \
                         BN0[1] = *(const v4i*)(qb1); }                     \
    SFENCE(); SBAR();                                                       \
    __builtin_amdgcn_s_setprio(1);                                          \
    acc[0][0] = MM(a1[0], BC1[0], acc[0][0]);                               \
    acc[0][1] = MM(a1[0], BC1[1], acc[0][1]);                               \
    acc[1][0] = MM(a1[1], BC1[0], acc[1][0]);                               \
    acc[1][1] = MM(a1[1], BC1[1], acc[1][1]);                               \
    __builtin_amdgcn_s_setprio(0);                                          \
    SFENCE(); SBAR(); SFENCE();                                             \
    /* ph3 */                                                               \
    a1[2] = RD_A(T0, 2, cs1);  a1[3] = RD_A(T0, 3, cs1);                    \
    if ((KT) + 1 < NT) { BN1[0] = *(const v4i*)(qb0 + 1024);                \
                         BN1[1] = *(const v4i*)(qb1 + 1024);                \
                         qb0 += 2048; qb1 += 2048; }                        \
    SFENCE(); SBAR();                                                       \
    __builtin_amdgcn_s_setprio(1);                                          \
    acc[2][0] = MM(a1[2], BC1[0], acc[2][0]);                               \
    acc[2][1] = MM(a1[2], BC1[1], acc[2][1]);                               \
    acc[3][0] = MM(a1[3], BC1[0], acc[3][0]);                               \
    acc[3][1] = MM(a1[3], BC1[1], acc[3][1]);                               \
    __builtin_amdgcn_s_setprio(0);                                          \
    SFENCE(); SBAR(); SFENCE();                                             \
    { signed char* t_ = T0; T0 = T1; T1 = T2; T2 = t_; }                    \
} while (0)

    for (int kt = 0; kt < NT; kt += 2) {
        TILE(bc0, bc1, bn0r, bn1r, kt);      // consumes b(kt), loads b(kt+1)
        TILE(bn0r, bn1r, bc0, bc1, kt + 1);  // consumes b(kt+1), loads b(kt+2)
    }
#undef TILE
#undef RD_A

    // Epilogue: C/D layout col=lane&31, row=(reg&3)+8*(reg>>2)+4*(lane>>5).
#pragma unroll
    for (int i = 0; i < 4; ++i) {
        const int mbase = bm0 + wr * 128 + i * 32 + 4 * kh;
#pragma unroll
        for (int j = 0; j < 2; ++j) {
            const int n = bn0 + wc * 64 + j * 32 + l31;
#pragma unroll
            for (int r = 0; r < 16; ++r) {
                const int m = mbase + (r & 3) + 8 * (r >> 2);
                out[(long)m * N_TOT + n] = acc[i][j][r];
            }
        }
    }
}

extern "C" void kernel_launch(void* const* d_in, const int* in_sizes, int n_in,
                              void* d_out, int out_size, void* d_ws, size_t ws_size,
                              hipStream_t stream) {
    const int* x32  = (const int*)d_in[0];  // [8192,4096] logical i8 as i32
    const int* w32  = (const int*)d_in[1];  // [4096,4096] logical i8 as i32
    const int* bias = (const int*)d_in[2];  // [4096] i32
    int*       out  = (int*)d_out;          // [8192,4096] i32

    signed char* xp = (signed char*)d_ws;
    signed char* wp = (signed char*)d_ws + (size_t)M_TOT * K_TOT;

    pack2<<<2048, 256, 0, stream>>>((const int4*)x32, (int4*)xp,
                                    (const int4*)w32, (int4*)wp);

    dim3 grid(N_TOT / 256, M_TOT / 256);  // (16, 32) = 512 blocks
    i8gemm_bias<<<grid, 512, 0, stream>>>(xp, wp, bias, out);
}

// Round 13
// 395.135 us; speedup vs baseline: 1.0936x; 1.0348x over previous
//
#include <hip/hip_runtime.h>
#include <stdint.h>

// W8A8B32O32 Linear: y[m][n] = sum_k x[m][k]*w[n][k] + bias[n]
// M=8192, N=4096, K=4096. Inputs arrive as int32 (one int per logical int8
// element); pack to int8 in d_ws, then run the i8 MFMA GEMM.
//
// FINAL FORM (session-best, R4 = 142.9 us gemm / 48% MfmaUtil, reverted
// after R5-R12 falsified every further lever):
//   barrier phasing (R5: -11us), zero-conflict layout (R6: -37us, proved
//   conflicts are hidden), BK=128 sync-halving (R7: neutral), B-from-global
//   (R8 gather: -43us; R9 pre-shuffled coalesced: neutral), antiphase wave
//   pairing (R10: -8us), 3 independent blocks/CU (R11: -40us, util FELL at
//   29% occupancy), fine-grained 8-phase (R12: -21us). The op plateaus at
//   ~45-48% MfmaUtil under every structure; only read/MFMA interleave (R3)
//   and 2 waves/SIMD (R4) ever moved it.
#define M_TOT 8192
#define N_TOT 4096
#define K_TOT 4096

typedef int v4i  __attribute__((ext_vector_type(4)));
typedef int v16i __attribute__((ext_vector_type(16)));

__device__ __forceinline__ void gload_lds16(const void* g, void* l) {
    __builtin_amdgcn_global_load_lds(
        (const __attribute__((address_space(1))) unsigned int*)g,
        (__attribute__((address_space(3))) unsigned int*)l,
        16, 0, 0);
}

// gfx9 s_waitcnt simm16: vmcnt[3:0]@[3:0], expcnt@[6:4], lgkmcnt@[11:8],
// vmcnt[5:4]@[15:14].
#define WAIT_V2_L0() __builtin_amdgcn_s_waitcnt(0x0072)  // vmcnt(2) lgkmcnt(0)
#define WAIT_V0_L0() __builtin_amdgcn_s_waitcnt(0x0070)  // vmcnt(0) lgkmcnt(0)
#define WAIT_V4()    __builtin_amdgcn_s_waitcnt(0x0f74)  // vmcnt(4), lgkm free
#define SBAR()       __builtin_amdgcn_s_barrier()
#define SFENCE()     __builtin_amdgcn_sched_barrier(0)

// ---- fused pack int32 -> int8: 64B loads -> 16B store per thread-iter ----
// BW-bound at 240 MB (~45 us); split and fused variants measure the same ->
// at the traffic floor.
__global__ __launch_bounds__(256) void pack2(
        const int4* __restrict__ xs, int4* __restrict__ xd,
        const int4* __restrict__ ws, int4* __restrict__ wd) {
    const int t = blockIdx.x * 256 + threadIdx.x;       // 0..524287
#pragma unroll
    for (int it = 0; it < 6; ++it) {
        const long g = (long)it * 524288 + t;
        const int4* __restrict__ src = (it < 4) ? xs : ws;
        int4* __restrict__ dst       = (it < 4) ? xd : wd;
        const long o = (it < 4) ? g : g - 2097152;
        int4 r;
        int* rp = (int*)&r;
#pragma unroll
        for (int q = 0; q < 4; ++q) {
            const int4 a = src[o * 4 + q];
            rp[q] = (a.x & 255) | ((a.y & 255) << 8) |
                    ((a.z & 255) << 16) | (a.w << 24);
        }
        dst[o] = r;
    }
}

// ---- GEMM: 512 threads = 8 waves (2/SIMD) computing a 256x256 tile -------
// Proven cadence (R4): triple-buffered LDS, counted vmcnt, 2-phase kk split,
// ONE barrier + ONE counted wait per K-iter. 2 waves/SIMD via
// __launch_bounds__(512,2): acc = 8 v16i = 128 AGPR + ~100 VGPR fits 256.
//
// Per K-iter (per wave; tile kt in A0/B0, kt+1 in A1/B1, kt+2 -> A2/B2):
//   1) ds_read kk=1 frags of kt (6)         (hidden under step 3)
//   2) issue 2 DMAs: A-half of kt+2
//   3) MFMA kk=0 x8 (setprio)
//   4) s_waitcnt vmcnt(2) lgkmcnt(0); s_barrier
//      [drains tile kt+1's 4 DMAs, keeps kt+2's 2 in flight; retires my reads]
//   5) ds_read kk=0 frags of kt+1 (6)       (hidden under step 7)
//   6) issue 2 DMAs: B-half of kt+2
//   7) MFMA kk=1 x8 (setprio)
//   rotate buffers.
// vmcnt ledger at step 4: outstanding = kt+1's 4 (issued last iter) + kt+2's
// 2 (step 2) = 6 -> vmcnt(2) == "kt+1 landed" (in-order decrement). Tail
// iters use vmcnt(0). Buffer-reuse proof: step-2/6 DMAs target the buffer of
// tile kt-1, whose last reads (iter kt-1 step 1) were retired by iter kt-1
// step 4's lgkmcnt(0) in EVERY wave before its barrier; our issue is after.
// Reads of kt+1 at step 5 are safe: each wave's own vmcnt drain of kt+1
// precedes the same barrier. Explicit waits are REQUIRED: compiler alias
// analysis does not connect global_load_lds's LDS write to the ds_reads.
// XOR chunk swizzle: stored_chunk = logical_chunk ^ ((row>>1)&3); staging
// stays linear-in-load-order (global_load_lds needs wave-uniform LDS base).
// Residual 4-way read conflicts are hidden (R6: zero-conflict layout gained
// nothing and broke coalescing).
__global__ __launch_bounds__(512, 2) void i8gemm_bias(
        const signed char* __restrict__ x,
        const signed char* __restrict__ w,
        const int* __restrict__ bias,
        int* __restrict__ out) {
    __shared__ __align__(16) signed char la[3][256 * 64];
    __shared__ __align__(16) signed char lb[3][256 * 64];

    const int tid  = threadIdx.x;
    const int lane = tid & 63;           // 0..63
    const int wv   = tid >> 6;           // wave 0..7
    const int l31  = lane & 31;
    const int kh   = lane >> 5;          // K-half this lane supplies to MFMA
    const int wr   = wv >> 2;            // quadrant row (0..1) -> 128 rows
    const int wc   = wv & 3;             // quadrant col (0..3) -> 64 cols

    // XCD-aware bijective swizzle (512 blocks, 512%8==0): XCD k gets a
    // contiguous swz-range -> 4 A-panels x all 16 B-panels per XCD.
    const int flat = blockIdx.y * gridDim.x + blockIdx.x;   // 0..511
    const int swz  = (flat & 7) * 64 + (flat >> 3);
    const int bn0  = (swz & 15) * 256;
    const int bm0  = (swz >> 4) * 256;

    // Fused bias: C/D col = lane&31 -> bias is lane-constant per fragment.
    int bv[2];
#pragma unroll
    for (int j = 0; j < 2; ++j) bv[j] = bias[bn0 + wc * 64 + j * 32 + l31];
    v16i acc[4][2];
#pragma unroll
    for (int i = 0; i < 4; ++i)
#pragma unroll
        for (int j = 0; j < 2; ++j)
#pragma unroll
            for (int r = 0; r < 16; ++r) acc[i][j][r] = bv[j];

    // Staging: wave wv covers rows [wv*32, wv*32+32) of both A and B tiles:
    // 2 issues x (64 lanes x 16 B) each. Issue i covers rows i*16+(lane>>2);
    // stored chunk = lane&3; fetched chunk = (lane&3) ^ ((row>>1)&3)
    // = (lane&3) ^ ((lane>>3)&3).
    const int fc = (lane & 3) ^ ((lane >> 3) & 3);
    const signed char* pa = x + (long)(bm0 + wv * 32 + (lane >> 2)) * K_TOT + fc * 16;
    const signed char* pb = w + (long)(bn0 + wv * 32 + (lane >> 2)) * K_TOT + fc * 16;
    const int lbase = wv * 32 * 64;      // byte offset of this wave's rows

    // Fragment reads: A row = wr*128 + i*32 + l31, B row = wc*64 + j*32 + l31
    // -> swizzle = (l31>>1)&3 (bases are 0 mod 8). Logical chunk kk*2+kh is
    // stored at position (kk*2+kh)^swr.
    const int swr  = (l31 >> 1) & 3;
    const int aoff = (wr * 128 + l31) * 64;
    const int boff = (wc * 64  + l31) * 64;
    const int cs0  = ((kh    ) ^ swr) * 16;   // kk=0 chunk byte offset
    const int cs1  = ((2 + kh) ^ swr) * 16;   // kk=1 chunk byte offset

    // Rotating buffer pointers: A0/B0 = tile kt, A1/B1 = kt+1, A2/B2 = kt+2.
    signed char* A0 = &la[0][0]; signed char* A1 = &la[1][0]; signed char* A2 = &la[2][0];
    signed char* B0 = &lb[0][0]; signed char* B1 = &lb[1][0]; signed char* B2 = &lb[2][0];

    // Prologue: stage tile 0 then tile 1 (grouped per tile: vmcnt decrements
    // in issue order). 4 DMAs per tile per wave (2 A-rows + 2 B-rows).
#pragma unroll
    for (int i = 0; i < 2; ++i) {
        gload_lds16(pa + (long)i * 16 * K_TOT, A0 + lbase + i * 1024);
        gload_lds16(pb + (long)i * 16 * K_TOT, B0 + lbase + i * 1024);
    }
#pragma unroll
    for (int i = 0; i < 2; ++i) {
        gload_lds16(pa + 64 + (long)i * 16 * K_TOT, A1 + lbase + i * 1024);
        gload_lds16(pb + 64 + (long)i * 16 * K_TOT, B1 + lbase + i * 1024);
    }
    WAIT_V4();                 // tile 0 landed (tile 1's 4 stay in flight)
    SBAR();
    SFENCE();

    // Preload kk=0 fragments of tile 0.
    v4i a0[4], b0[2], a1[4], b1[2];
#pragma unroll
    for (int i = 0; i < 4; ++i) a0[i] = *(const v4i*)(A0 + aoff + i * 2048 + cs0);
#pragma unroll
    for (int j = 0; j < 2; ++j) b0[j] = *(const v4i*)(B0 + boff + j * 2048 + cs0);

    const int NT = K_TOT / 64;           // 64 K-tiles
    for (int kt = 0; kt < NT; ++kt) {
        SFENCE();
        // 1) ds_read kk=1 of tile kt (consumed by step 7; hidden by step 3).
#pragma unroll
        for (int i = 0; i < 4; ++i) a1[i] = *(const v4i*)(A0 + aoff + i * 2048 + cs1);
#pragma unroll
        for (int j = 0; j < 2; ++j) b1[j] = *(const v4i*)(B0 + boff + j * 2048 + cs1);
        SFENCE();
        // 2) Issue A-half prefetch of tile kt+2 (fire-and-forget).
        if (kt + 2 < NT) {
            const long k0 = (long)(kt + 2) * 64;
#pragma unroll
            for (int i = 0; i < 2; ++i)
                gload_lds16(pa + k0 + (long)i * 16 * K_TOT, A2 + lbase + i * 1024);
        }
        SFENCE();
        // 3) MFMA kk=0 (8): hides step-1 reads and step-2 issues.
        __builtin_amdgcn_s_setprio(1);
#pragma unroll
        for (int i = 0; i < 4; ++i)
#pragma unroll
            for (int j = 0; j < 2; ++j)
                acc[i][j] = __builtin_amdgcn_mfma_i32_32x32x32_i8(
                    a0[i], b0[j], acc[i][j], 0, 0, 0);
        __builtin_amdgcn_s_setprio(0);
        SFENCE();
        // 4) Publish/acquire: tile kt+1 landed everywhere, my reads retired.
        if (kt + 2 < NT) { WAIT_V2_L0(); } else { WAIT_V0_L0(); }
        SFENCE();
        SBAR();
        SFENCE();
        // 5) ds_read kk=0 of tile kt+1 (hidden by step 7).
        if (kt + 1 < NT) {
#pragma unroll
            for (int i = 0; i < 4; ++i) a0[i] = *(const v4i*)(A1 + aoff + i * 2048 + cs0);
#pragma unroll
            for (int j = 0; j < 2; ++j) b0[j] = *(const v4i*)(B1 + boff + j * 2048 + cs0);
        }
        SFENCE();
        // 6) Issue B-half prefetch of tile kt+2 (fire-and-forget).
        if (kt + 2 < NT) {
            const long k0 = (long)(kt + 2) * 64;
#pragma unroll
            for (int i = 0; i < 2; ++i)
                gload_lds16(pb + k0 + (long)i * 16 * K_TOT, B2 + lbase + i * 1024);
        }
        SFENCE();
        // 7) MFMA kk=1 (8): hides step-5 reads (a1/b1 drained at step 4).
        __builtin_amdgcn_s_setprio(1);
#pragma unroll
        for (int i = 0; i < 4; ++i)
#pragma unroll
            for (int j = 0; j < 2; ++j)
                acc[i][j] = __builtin_amdgcn_mfma_i32_32x32x32_i8(
                    a1[i], b1[j], acc[i][j], 0, 0, 0);

        // Rotate buffers (register pointer swap, no dynamic indexing).
        signed char* t;
        t = A0; A0 = A1; A1 = A2; A2 = t;
        t = B0; B0 = B1; B1 = B2; B2 = t;
    }

    // Epilogue: C/D layout col=lane&31, row=(reg&3)+8*(reg>>2)+4*(lane>>5).
#pragma unroll
    for (int i = 0; i < 4; ++i) {
        const int mbase = bm0 + wr * 128 + i * 32 + 4 * kh;
#pragma unroll
        for (int j = 0; j < 2; ++j) {
            const int n = bn0 + wc * 64 + j * 32 + l31;
#pragma unroll
            for (int r = 0; r < 16; ++r) {
                const int m = mbase + (r & 3) + 8 * (r >> 2);
                out[(long)m * N_TOT + n] = acc[i][j][r];
            }
        }
    }
}

extern "C" void kernel_launch(void* const* d_in, const int* in_sizes, int n_in,
                              void* d_out, int out_size, void* d_ws, size_t ws_size,
                              hipStream_t stream) {
    const int* x32  = (const int*)d_in[0];  // [8192,4096] logical i8 as i32
    const int* w32  = (const int*)d_in[1];  // [4096,4096] logical i8 as i32
    const int* bias = (const int*)d_in[2];  // [4096] i32
    int*       out  = (int*)d_out;          // [8192,4096] i32

    signed char* xp = (signed char*)d_ws;
    signed char* wp = (signed char*)d_ws + (size_t)M_TOT * K_TOT;

    pack2<<<2048, 256, 0, stream>>>((const int4*)x32, (int4*)xp,
                                    (const int4*)w32, (int4*)wp);

    dim3 grid(N_TOT / 256, M_TOT / 256);  // (16, 32)
    i8gemm_bias<<<grid, 512, 0, stream>>>(xp, wp, bias, out);
}